// Round 7
// baseline (1586.274 us; speedup 1.0000x reference)
//
#include <hip/hip_runtime.h>

// GPFA e-step posterior mean on MI355X — direct Kronecker-sum solve, fp32 chains.
// M = Kbar (x) I_F + I_T (x) A,  Kbar = sum_f inv(K_f),  A = C'R^-1 C = V Lam V'.
// Per factor-eigenpair i: (Kbar + lam_i I) xt_i = bt_i  (512x512, 128 RHS).
// GJ chains: one apply-kernel per step (pure tile GEMMs, pivot inverse read from
// global); the NEXT step's 64x64 pivot inversion is fused into the single
// designated block that produces tile (k+1,k+1).
//
// R2: eig8 wave-parallel via shfl.
// R4: term1 chunked over 4 n-chunks.
// R5 FAILED: straight-lined GJ -> I-cache thrash. R6: rotation register GJ
// (pivot row always in c0) fixed scratch+icache but stayed ~50us/tail.
// R7: broadcast via __shfl (ds_bpermute, VGPR pipe) instead of readlane.
// Theory: v_readlane's SGPR destination serialized the 63 independent
// broadcasts per step (SGPR reuse -> RAW/WAR chain ~12-16cyc/row); bpermute
// keeps them in the pipelined LDS-permute path (~6cyc issue, no SGPR hazard).
// Same broadcast values -> numerics bit-identical.

#define NF 8
#define TBINS 512
#define NNEU 512
#define NTRI 128
#define PAD 68

// ---- ws layout (float offsets) ----
#define OFF_A0     0                 // float[8*512*512] ping (reused as term1 partials)
#define OFF_A1     2097152           // float[8*512*512] pong
#define OFF_CRVT   4194304           // float[512*8]
#define OFF_CRVVT  4198400           // float[512*8]
#define OFF_CCT    4202496           // float[64]
#define OFF_CD     4202560           // float[64]
#define OFF_CDV    4202624           // float[64]
#define OFF_RINV   4202688           // float[512]
#define OFF_LAM    4203200           // float[8]
#define OFF_VF     4203216           // float[64]
#define OFF_BT     4203280           // float[4096*128]
#define OFF_XT     4727568           // float[4096*128]
#define OFF_PP0    5251856           // float[8*4096] pivot-inverse buf A
#define OFF_PP1    5284624           // float[8*4096] pivot-inverse buf B

__device__ __forceinline__ void load8(float* v, const float* ptr){
  float4 a = ((const float4*)ptr)[0];
  float4 b = ((const float4*)ptr)[1];
  v[0]=a.x; v[1]=a.y; v[2]=a.z; v[3]=a.w;
  v[4]=b.x; v[5]=b.y; v[6]=b.z; v[7]=b.w;
}
__device__ __forceinline__ void store8(float* ptr, const float* v){
  ((float4*)ptr)[0] = make_float4(v[0],v[1],v[2],v[3]);
  ((float4*)ptr)[1] = make_float4(v[4],v[5],v[6],v[7]);
}

// ---------------- named-scalar machinery ----------------
#define REP64A(M) M(0) M(1) M(2) M(3) M(4) M(5) M(6) M(7) M(8) M(9) M(10) M(11) M(12) M(13) M(14) M(15) \
  M(16) M(17) M(18) M(19) M(20) M(21) M(22) M(23) M(24) M(25) M(26) M(27) M(28) M(29) M(30) M(31) \
  M(32) M(33) M(34) M(35) M(36) M(37) M(38) M(39) M(40) M(41) M(42) M(43) M(44) M(45) M(46) M(47) \
  M(48) M(49) M(50) M(51) M(52) M(53) M(54) M(55) M(56) M(57) M(58) M(59) M(60) M(61) M(62) M(63)

// pairs (p, p-1) for the fused update+rotate, p = 1..63
#define REP63P(M) M(1,0) M(2,1) M(3,2) M(4,3) M(5,4) M(6,5) M(7,6) M(8,7) M(9,8) M(10,9) \
  M(11,10) M(12,11) M(13,12) M(14,13) M(15,14) M(16,15) M(17,16) M(18,17) M(19,18) M(20,19) \
  M(21,20) M(22,21) M(23,22) M(24,23) M(25,24) M(26,25) M(27,26) M(28,27) M(29,28) M(30,29) \
  M(31,30) M(32,31) M(33,32) M(34,33) M(35,34) M(36,35) M(37,36) M(38,37) M(39,38) M(40,39) \
  M(41,40) M(42,41) M(43,42) M(44,43) M(45,44) M(46,45) M(47,46) M(48,47) M(49,48) M(50,49) \
  M(51,50) M(52,51) M(53,52) M(54,53) M(55,54) M(56,55) M(57,56) M(58,57) M(59,58) M(60,59) \
  M(61,60) M(62,61) M(63,62)

#define DECLC(i) float c##i;

// one fused update+rotate: physical reg p holds row (p+kk)%64; after this, reg
// p-1 holds that row's UPDATED value (so next step's pivot row lands in c0).
// Broadcast via __shfl -> ds_bpermute (VGPR pipe, pipelined; NOT readlane/SGPR).
#define GJ_UPDROT(p, pm1) { float pc = __shfl(c##p, kk, 64); \
  float bs = iskk ? 0.0f : c##p; \
  c##pm1 = fmaf(-pc, t0, bs); }

// the 64-step runtime loop over named scalars c0..c63 (lane = column index)
#define GJ_LOOP \
  for (int kk = 0; kk < 64; ++kk){ \
    float pivot = __shfl(c0, kk, 64); \
    float pinv  = 1.0f / pivot; \
    bool  iskk  = (lane == kk); \
    float newr  = c0 * pinv; \
    float t0    = iskk ? pinv : newr; \
    REP63P(GJ_UPDROT) \
    c63 = t0; \
  }

// ---------------- prep ----------------
__global__ void prep_kernel(const float* __restrict__ Cm, const float* __restrict__ dm,
                            const float* __restrict__ r_diag,
                            float* __restrict__ crvT, float* __restrict__ ccT,
                            float* __restrict__ cd, float* __restrict__ rinv){
  __shared__ float s_crv[NNEU*NF];
  __shared__ float s_cm[NNEU*NF];
  __shared__ float s_dm[NNEU];
  int tid = threadIdx.x;            // 512; thread == neuron n
  float ri = 1.0f / r_diag[tid];
  rinv[tid] = ri;
  s_dm[tid] = dm[tid];
  #pragma unroll
  for (int f = 0; f < NF; ++f){
    float cv = Cm[tid*NF + f];
    s_cm[tid*NF + f] = cv;
    float v = cv * ri;
    s_crv[tid*NF + f] = v;
    crvT[tid*NF + f] = v;
  }
  __syncthreads();
  if (tid < 64){
    int f = tid >> 3, g = tid & 7;
    float acc = 0.f;
    for (int n = 0; n < NNEU; ++n) acc += s_crv[n*NF+f] * s_cm[n*NF+g];
    ccT[tid] = acc;
  } else if (tid < 72){
    int f = tid - 64;
    float acc = 0.f;
    for (int n = 0; n < NNEU; ++n) acc += s_crv[n*NF+f] * s_dm[n];
    cd[f] = acc;
  }
}

// ---------------- 8x8 eig: cyclic Jacobi, wave-parallel, fp32 ----------------
__global__ void eig8_kernel(const float* __restrict__ ccT,
                            float* __restrict__ Vf, float* __restrict__ lam){
  int lane = threadIdx.x & 63;      // one wave, 64 lanes
  int a = lane >> 3, b = lane & 7;
  float Av = ccT[lane];
  float Vv = (a == b) ? 1.0f : 0.0f;
  for (int sw = 0; sw < 8; ++sw){
    for (int p = 0; p < 7; ++p){
      for (int q = p + 1; q < 8; ++q){
        float apq = __shfl(Av, p*8 + q, 64);
        if (fabsf(apq) < 1e-20f) continue;          // uniform: apq is wave-broadcast
        float app = __shfl(Av, p*8 + p, 64);
        float aqq = __shfl(Av, q*8 + q, 64);
        float beta = (aqq - app) / (2.0f * apq);
        float tt = ((beta >= 0.0f) ? 1.0f : -1.0f) / (fabsf(beta) + sqrtf(1.0f + beta*beta));
        float c = 1.0f / sqrtf(1.0f + tt*tt);
        float s = tt * c;
        int bp = (b == p) ? q : (b == q) ? p : b;   // partner column
        float Ac = __shfl(Av, a*8 + bp, 64);        // snapshot before writes
        float Vc = __shfl(Vv, a*8 + bp, 64);
        if (b == p)      { Av = c*Av - s*Ac;  Vv = c*Vv - s*Vc; }
        else if (b == q) { Av = s*Ac + c*Av;  Vv = s*Vc + c*Vv; }
        int ap = (a == p) ? q : (a == q) ? p : a;   // partner row
        float Ar = __shfl(Av, ap*8 + b, 64);
        if (a == p)      Av = c*Av - s*Ar;
        else if (a == q) Av = s*Ar + c*Av;
      }
    }
  }
  if (a == b) lam[a] = Av;
  Vf[lane] = Vv;
}

// ---------------- rotate crv, cd by V^T ----------------
__global__ void rotv_kernel(const float* __restrict__ crvT, const float* __restrict__ cd,
                            const float* __restrict__ Vf,
                            float* __restrict__ crvVT, float* __restrict__ cdV){
  __shared__ float Vl[64];
  int tid = threadIdx.x;   // 512
  if (tid < 64) Vl[tid] = Vf[tid];
  __syncthreads();
  float cv[8], ov[8];
  load8(cv, crvT + tid*8);
  #pragma unroll
  for (int i = 0; i < 8; ++i){
    float s = 0.f;
    #pragma unroll
    for (int f = 0; f < 8; ++f) s += Vl[f*8+i] * cv[f];
    ov[i] = s;
  }
  store8(crvVT + tid*8, ov);
  if (tid < 8){
    float s = 0.f;
    #pragma unroll
    for (int f = 0; f < 8; ++f) s += Vl[f*8+tid] * cd[f];
    cdV[tid] = s;
  }
}

// ---------------- build K_f (fp32) ----------------
__global__ void buildK_kernel(const float* __restrict__ gamma, float* __restrict__ A0){
  int f = blockIdx.y;
  int idx = blockIdx.x*256 + threadIdx.x;   // t*512+u
  int t = idx >> 9, u = idx & 511;
  float g = gamma[f];
  float d = (float)(t - u);
  float v = 0.999f * expf(-0.5f * g * d * d);
  if (t == u) v += 1.0e-3f;
  A0[(size_t)f*TBINS*TBINS + idx] = v;
}

// ---------------- G_i = (sum_f Kinv_f) + lam_i I ----------------
__global__ void buildG_kernel(const float* __restrict__ A0, const float* __restrict__ lam,
                              float* __restrict__ A1){
  int idx = blockIdx.x*256 + threadIdx.x;       // 0..262143
  float s = 0.f;
  #pragma unroll
  for (int f2 = 0; f2 < NF; ++f2) s += A0[(size_t)f2*TBINS*TBINS + idx];
  bool diag = ((idx >> 9) == (idx & 511));
  #pragma unroll
  for (int i = 0; i < NF; ++i)
    A1[(size_t)i*TBINS*TBINS + idx] = s + (diag ? lam[i] : 0.f);
}

// ---------------- standalone pivot inversion (chain head): Pout = inv(A[f][0:64][0:64]) ----------------
// One wave per factor; lane owns column `lane`, rows in rotating named scalars.
__global__ __launch_bounds__(64) void gj_pivot0(const float* __restrict__ A,
                                                float* __restrict__ Pout){
  int f = blockIdx.x;
  int lane = threadIdx.x;           // 64
  const float* Af = A + (size_t)f*TBINS*TBINS;
  REP64A(DECLC)
  #define LOADG(i) c##i = Af[(size_t)(i)*TBINS + lane];
  REP64A(LOADG)
  #undef LOADG
  GJ_LOOP
  #define STOREC(i) Pout[(f<<12) + (i)*64 + lane] = c##i;
  REP64A(STOREC)
  #undef STOREC
}

// ---------------- GJ apply step: src -> dst; pivot inverse from Pin; designated
// block (k+1,k+1) also inverts its output tile -> Pout ----------------
#define ACC4(tm, fm) \
  tm[0] += fm.x*s0.x + fm.y*s1.x + fm.z*s2.x + fm.w*s3.x; \
  tm[1] += fm.x*s0.y + fm.y*s1.y + fm.z*s2.y + fm.w*s3.y; \
  tm[2] += fm.x*s0.z + fm.y*s1.z + fm.z*s2.z + fm.w*s3.z; \
  tm[3] += fm.x*s0.w + fm.y*s1.w + fm.z*s2.w + fm.w*s3.w;

__global__ __launch_bounds__(256) void gj_apply(const float* __restrict__ src,
                                                float* __restrict__ dst,
                                                const float* __restrict__ Pin,
                                                float* __restrict__ Pout,
                                                int k, int inv_next){
  __shared__ float P[64*PAD];
  __shared__ float Q[64*PAD];
  __shared__ float F[64*PAD];
  int f  = blockIdx.y;
  int ti = blockIdx.x >> 3, tj = blockIdx.x & 7;
  int tid = threadIdx.x;
  const float* A = src + (size_t)f*TBINS*TBINS;
  float* D = dst + (size_t)f*TBINS*TBINS;

  // load pivot inverse (precomputed)
  for (int v = tid; v < 1024; v += 256){
    int r = v >> 4, c4 = (v & 15) << 2;
    *(float4*)&P[r*PAD + c4] = *(const float4*)(Pin + f*4096 + r*64 + c4);
  }
  if (tj != k){
    for (int v = tid; v < 1024; v += 256){
      int r = v >> 4, c4 = (v & 15) << 2;
      *(float4*)&Q[r*PAD + c4] = *(const float4*)(A + (size_t)(k*64+r)*TBINS + tj*64 + c4);
    }
  }
  if (ti != k){
    for (int v = tid; v < 1024; v += 256){
      int r = v >> 4, c4 = (v & 15) << 2;
      *(float4*)&F[r*PAD + c4] = *(const float4*)(A + (size_t)(ti*64+r)*TBINS + k*64 + c4);
    }
  }
  __syncthreads();

  int jg = (tid & 15) << 2;   // output cols jg..jg+3
  int ib = (tid >> 4) << 2;   // output rows ib..ib+3

  if (tj == k){
    if (ti == k){
      // pass-through: D[k][k] = P
      for (int v = tid; v < 1024; v += 256){
        int r = v >> 4, c4 = (v & 15) << 2;
        *(float4*)(D + (size_t)(k*64+r)*TBINS + k*64 + c4) = *(float4*)&P[r*PAD + c4];
      }
      return;
    }
    // D = -F @ P
    float w[4][4] = {{0.f,0.f,0.f,0.f},{0.f,0.f,0.f,0.f},{0.f,0.f,0.f,0.f},{0.f,0.f,0.f,0.f}};
    for (int u4 = 0; u4 < 64; u4 += 4){
      float4 f0 = *(float4*)&F[(ib+0)*PAD + u4];
      float4 f1 = *(float4*)&F[(ib+1)*PAD + u4];
      float4 f2 = *(float4*)&F[(ib+2)*PAD + u4];
      float4 f3 = *(float4*)&F[(ib+3)*PAD + u4];
      float4 s0 = *(float4*)&P[(u4+0)*PAD + jg];
      float4 s1 = *(float4*)&P[(u4+1)*PAD + jg];
      float4 s2 = *(float4*)&P[(u4+2)*PAD + jg];
      float4 s3 = *(float4*)&P[(u4+3)*PAD + jg];
      ACC4(w[0], f0); ACC4(w[1], f1); ACC4(w[2], f2); ACC4(w[3], f3);
    }
    #pragma unroll
    for (int m = 0; m < 4; ++m)
      *(float4*)(D + (size_t)(ti*64+ib+m)*TBINS + k*64 + jg)
        = make_float4(-w[m][0], -w[m][1], -w[m][2], -w[m][3]);
    return;
  }

  // tj != k: T = P @ Q (P symmetric: P'[ib][u] = P[u][ib])
  float t[4][4] = {{0.f,0.f,0.f,0.f},{0.f,0.f,0.f,0.f},{0.f,0.f,0.f,0.f},{0.f,0.f,0.f,0.f}};
  for (int u = 0; u < 64; ++u){
    float4 pv = *(float4*)&P[u*PAD + ib];
    float4 qv = *(float4*)&Q[u*PAD + jg];
    t[0][0]+=pv.x*qv.x; t[0][1]+=pv.x*qv.y; t[0][2]+=pv.x*qv.z; t[0][3]+=pv.x*qv.w;
    t[1][0]+=pv.y*qv.x; t[1][1]+=pv.y*qv.y; t[1][2]+=pv.y*qv.z; t[1][3]+=pv.y*qv.w;
    t[2][0]+=pv.z*qv.x; t[2][1]+=pv.z*qv.y; t[2][2]+=pv.z*qv.z; t[2][3]+=pv.z*qv.w;
    t[3][0]+=pv.w*qv.x; t[3][1]+=pv.w*qv.y; t[3][2]+=pv.w*qv.z; t[3][3]+=pv.w*qv.w;
  }
  if (ti == k){
    // D = T directly from registers
    #pragma unroll
    for (int m = 0; m < 4; ++m)
      *(float4*)(D + (size_t)(k*64+ib+m)*TBINS + tj*64 + jg)
        = make_float4(t[m][0],t[m][1],t[m][2],t[m][3]);
    return;
  }
  __syncthreads();               // all reads of Q done
  #pragma unroll
  for (int m = 0; m < 4; ++m)
    *(float4*)&Q[(ib+m)*PAD + jg] = make_float4(t[m][0],t[m][1],t[m][2],t[m][3]);
  __syncthreads();               // T visible to all

  // Schur: D = A[ti][tj] - F @ T
  float w[4][4] = {{0.f,0.f,0.f,0.f},{0.f,0.f,0.f,0.f},{0.f,0.f,0.f,0.f},{0.f,0.f,0.f,0.f}};
  for (int u4 = 0; u4 < 64; u4 += 4){
    float4 f0 = *(float4*)&F[(ib+0)*PAD + u4];
    float4 f1 = *(float4*)&F[(ib+1)*PAD + u4];
    float4 f2 = *(float4*)&F[(ib+2)*PAD + u4];
    float4 f3 = *(float4*)&F[(ib+3)*PAD + u4];
    float4 s0 = *(float4*)&Q[(u4+0)*PAD + jg];
    float4 s1 = *(float4*)&Q[(u4+1)*PAD + jg];
    float4 s2 = *(float4*)&Q[(u4+2)*PAD + jg];
    float4 s3 = *(float4*)&Q[(u4+3)*PAD + jg];
    ACC4(w[0], f0); ACC4(w[1], f1); ACC4(w[2], f2); ACC4(w[3], f3);
  }
  #pragma unroll
  for (int m = 0; m < 4; ++m){
    float4 av = *(const float4*)(A + (size_t)(ti*64+ib+m)*TBINS + tj*64 + jg);
    float4 dv = make_float4(av.x - w[m][0], av.y - w[m][1], av.z - w[m][2], av.w - w[m][3]);
    *(float4*)(D + (size_t)(ti*64+ib+m)*TBINS + tj*64 + jg) = dv;
    w[m][0] = dv.x; w[m][1] = dv.y; w[m][2] = dv.z; w[m][3] = dv.w;
  }

  // designated block: next step's pivot inverse via single-wave rotating register GJ
  if (inv_next && ti == k+1 && tj == k+1){
    __syncthreads();
    #pragma unroll
    for (int m = 0; m < 4; ++m)
      *(float4*)&P[(ib+m)*PAD + jg] = make_float4(w[m][0],w[m][1],w[m][2],w[m][3]);
    __syncthreads();
    if (tid < 64){
      int lane = tid;
      REP64A(DECLC)
      #define LOADL(i) c##i = P[(i)*PAD + lane];
      REP64A(LOADL)
      #undef LOADL
      GJ_LOOP
      #define STOREC(i) Pout[(f<<12) + (i)*64 + lane] = c##i;
      REP64A(STOREC)
      #undef STOREC
    }
  }
}

// ---------------- term1 (chunked): btp[z][(t*8+i)*128+c] = sum_{n in chunk z} crvV[i][n] spike[c][n][t]
__global__ void term1_kernel(const float* __restrict__ spike, const float* __restrict__ crvVT,
                             float* __restrict__ btp){
  __shared__ float crl[128*NF];    // this chunk's [n][i]
  __shared__ float ot[128][17];
  int t0 = blockIdx.x * 16;
  int c0 = blockIdx.y * 16;
  int n0 = blockIdx.z << 7;        // 128-neuron chunk
  int tid = threadIdx.x;           // 256
  int tl = tid & 15, cl = tid >> 4;
  ((float4*)crl)[tid] = ((const float4*)(crvVT + n0*NF))[tid];   // 1024 floats
  __syncthreads();
  float acc[8] = {0.f,0.f,0.f,0.f,0.f,0.f,0.f,0.f};
  const float* Sp = spike + (size_t)(c0+cl)*NNEU*TBINS + (size_t)n0*TBINS + t0 + tl;
  for (int n = 0; n < 128; n += 8){
    float s[8];
    #pragma unroll
    for (int j = 0; j < 8; ++j) s[j] = Sp[(size_t)(n+j)*TBINS];   // 8 loads in flight
    #pragma unroll
    for (int j = 0; j < 8; ++j){
      float4 ca = *(float4*)&crl[(n+j)*8];
      float4 cb = *(float4*)&crl[(n+j)*8+4];
      acc[0] += ca.x*s[j]; acc[1] += ca.y*s[j]; acc[2] += ca.z*s[j]; acc[3] += ca.w*s[j];
      acc[4] += cb.x*s[j]; acc[5] += cb.y*s[j]; acc[6] += cb.z*s[j]; acc[7] += cb.w*s[j];
    }
  }
  #pragma unroll
  for (int i = 0; i < 8; ++i) ot[tl*8+i][cl] = acc[i];
  __syncthreads();
  int row = tid >> 1, off = (tid & 1) * 8;    // row = tlocal*8+i
  int tt = t0 + (row >> 3), ii = row & 7;
  float* dst = btp + (size_t)blockIdx.z*524288 + (size_t)(tt*8+ii)*NTRI + c0 + off;
  #pragma unroll
  for (int k = 0; k < 8; ++k) dst[k] = ot[row][off+k];
}

// ---------------- term1 reduce: bt = sum_z btp[z] - cdV[i] ----------------
__global__ void term1_reduce(const float* __restrict__ btp, const float* __restrict__ cdV,
                             float* __restrict__ bt){
  int idx = blockIdx.x*256 + threadIdx.x;   // float4 index, 131072 total
  const float4* p = (const float4*)btp;
  float4 a = p[idx];
  float4 b = p[idx + 131072];
  float4 c = p[idx + 262144];
  float4 d = p[idx + 393216];
  float cv = cdV[(idx >> 5) & 7];           // i = ((t*8+i)*32 + c4)>>5 & 7
  ((float4*)bt)[idx] = make_float4(a.x+b.x+c.x+d.x - cv,
                                   a.y+b.y+c.y+d.y - cv,
                                   a.z+b.z+c.z+d.z - cv,
                                   a.w+b.w+c.w+d.w - cv);
}

// ---------------- batched GEMM: xt_i = H_i (512x512) @ bt_i (512x128) ----------------
__global__ void gemm_kernel(const float* __restrict__ H, const float* __restrict__ bt,
                            float* __restrict__ xt){
  __shared__ float Ht[32][68];
  __shared__ float Bt[64][128];
  int i  = blockIdx.y;
  int t0 = blockIdx.x * 32;
  int tid = threadIdx.x;           // 256
  int gt = tid >> 5;               // 0..7
  int gc = tid & 31;               // 0..31
  float acc[4][4] = {{0.f,0.f,0.f,0.f},{0.f,0.f,0.f,0.f},{0.f,0.f,0.f,0.f},{0.f,0.f,0.f,0.f}};
  const float* Hi = H + (size_t)i*TBINS*TBINS;
  for (int uc = 0; uc < 8; ++uc){
    int u0 = uc*64;
    __syncthreads();
    for (int v = tid; v < 512; v += 256){
      int r = v >> 4, c4 = (v & 15) << 2;
      *(float4*)&Ht[r][c4] = *(const float4*)(Hi + (size_t)(t0+r)*TBINS + u0 + c4);
    }
    for (int v = tid; v < 2048; v += 256){
      int r = v >> 5, c4 = (v & 31) << 2;
      *(float4*)&Bt[r][c4] = *(const float4*)(bt + (size_t)((u0+r)*8 + i)*NTRI + c4);
    }
    __syncthreads();
    for (int u = 0; u < 64; ++u){
      float h0 = Ht[gt*4+0][u], h1 = Ht[gt*4+1][u], h2 = Ht[gt*4+2][u], h3 = Ht[gt*4+3][u];
      float b0 = Bt[u][gc], b1 = Bt[u][gc+32], b2 = Bt[u][gc+64], b3 = Bt[u][gc+96];
      acc[0][0] += h0*b0; acc[0][1] += h0*b1; acc[0][2] += h0*b2; acc[0][3] += h0*b3;
      acc[1][0] += h1*b0; acc[1][1] += h1*b1; acc[1][2] += h1*b2; acc[1][3] += h1*b3;
      acc[2][0] += h2*b0; acc[2][1] += h2*b1; acc[2][2] += h2*b2; acc[2][3] += h2*b3;
      acc[3][0] += h3*b0; acc[3][1] += h3*b1; acc[3][2] += h3*b2; acc[3][3] += h3*b3;
    }
  }
  #pragma unroll
  for (int m = 0; m < 4; ++m)
    #pragma unroll
    for (int j = 0; j < 4; ++j)
      xt[(size_t)((t0 + gt*4 + m)*8 + i)*NTRI + gc + 32*j] = acc[m][j];
}

// ---------------- output: out[c][f][t] = sum_i V[f][i] xt[(t*8+i)*128+c] ----------------
__global__ void output_kernel(const float* __restrict__ xt, const float* __restrict__ Vf,
                              float* __restrict__ out){
  __shared__ float T[128][68];
  __shared__ float Vl[64];
  int t0 = blockIdx.x * 64, c0 = blockIdx.y * 16;
  int tid = threadIdx.x;   // 256
  if (tid < 64) Vl[tid] = Vf[tid];
  __syncthreads();
  for (int idx = tid; idx < 1024; idx += 256){
    int tl = idx >> 4, cl = idx & 15;
    float xv[8];
    #pragma unroll
    for (int i = 0; i < 8; ++i)
      xv[i] = xt[(size_t)((t0+tl)*8+i)*NTRI + c0 + cl];
    #pragma unroll
    for (int f = 0; f < 8; ++f){
      float s = 0.f;
      #pragma unroll
      for (int i = 0; i < 8; ++i) s += Vl[f*8+i] * xv[i];
      T[cl*8+f][tl] = s;
    }
  }
  __syncthreads();
  int row = tid >> 1, half = tid & 1;   // row = cl*8+f
  int cc = c0 + (row >> 3), ff = row & 7;
  float* dst = out + (size_t)cc*NF*TBINS + ff*TBINS + t0 + half*32;
  #pragma unroll
  for (int k = 0; k < 8; ++k)
    ((float4*)dst)[k] = *(float4*)&T[row][half*32 + k*4];
}

extern "C" void kernel_launch(void* const* d_in, const int* in_sizes, int n_in,
                              void* d_out, int out_size, void* d_ws, size_t ws_size,
                              hipStream_t stream) {
  const float* spike  = (const float*)d_in[0];
  const float* Cm     = (const float*)d_in[1];
  const float* dm     = (const float*)d_in[2];
  const float* r_diag = (const float*)d_in[3];
  const float* gamma  = (const float*)d_in[4];
  float* out = (float*)d_out;
  float* ws = (float*)d_ws;

  float*  A0    = ws + OFF_A0;
  float*  A1    = ws + OFF_A1;
  float*  crvT  = ws + OFF_CRVT;
  float*  crvVT = ws + OFF_CRVVT;
  float*  ccT   = ws + OFF_CCT;
  float*  cd    = ws + OFF_CD;
  float*  cdV   = ws + OFF_CDV;
  float*  rinv  = ws + OFF_RINV;
  float*  lam   = ws + OFF_LAM;
  float*  Vf    = ws + OFF_VF;
  float*  bt    = ws + OFF_BT;
  float*  xt    = ws + OFF_XT;
  float*  Pb[2] = { ws + OFF_PP0, ws + OFF_PP1 };

  prep_kernel<<<1, 512, 0, stream>>>(Cm, dm, r_diag, crvT, ccT, cd, rinv);
  eig8_kernel<<<1, 64, 0, stream>>>(ccT, Vf, lam);
  rotv_kernel<<<1, 512, 0, stream>>>(crvT, cd, Vf, crvVT, cdV);
  buildK_kernel<<<dim3(1024, 8), 256, 0, stream>>>(gamma, A0);

  // chain 1: invert K_f (ping-pong A0 <-> A1, 8 steps -> result in A0)
  gj_pivot0<<<8, 64, 0, stream>>>(A0, Pb[0]);
  {
    float* s = A0; float* d = A1;
    for (int k = 0; k < 8; ++k){
      gj_apply<<<dim3(64, 8), 256, 0, stream>>>(s, d, Pb[k&1], Pb[(k+1)&1], k, (k < 7) ? 1 : 0);
      float* tmp = s; s = d; d = tmp;
    }
  }
  buildG_kernel<<<1024, 256, 0, stream>>>(A0, lam, A1);
  // chain 2: invert G_i (start A1, 8 steps -> H in A1; A0 dead afterwards)
  gj_pivot0<<<8, 64, 0, stream>>>(A1, Pb[0]);
  {
    float* s = A1; float* d = A0;
    for (int k = 0; k < 8; ++k){
      gj_apply<<<dim3(64, 8), 256, 0, stream>>>(s, d, Pb[k&1], Pb[(k+1)&1], k, (k < 7) ? 1 : 0);
      float* tmp = s; s = d; d = tmp;
    }
  }
  term1_kernel<<<dim3(32, 8, 4), 256, 0, stream>>>(spike, crvVT, A0);
  term1_reduce<<<512, 256, 0, stream>>>(A0, cdV, bt);
  gemm_kernel<<<dim3(16, 8), 256, 0, stream>>>(A1, bt, xt);
  output_kernel<<<dim3(8, 8), 256, 0, stream>>>(xt, Vf, out);
}

// Round 9
// 1191.074 us; speedup vs baseline: 1.3318x; 1.3318x over previous
//
#include <hip/hip_runtime.h>

// GPFA e-step posterior mean on MI355X — direct Kronecker-sum solve, fp32 chains.
// M = Kbar (x) I_F + I_T (x) A,  Kbar = sum_f inv(K_f),  A = C'R^-1 C = V Lam V'.
// Per factor-eigenpair i: (Kbar + lam_i I) xt_i = bt_i  (512x512, 128 RHS).
//
// R2: eig8 wave-parallel via shfl.  R4: term1 chunked.
// R5 FAILED: straight-line GJ -> I-cache thrash. R6/R7: rotation register GJ;
// readlane vs shfl broadcast made NO difference (79/77/80us) -> serialization
// is scheduler-level (one broadcast+use at a time, ~30cyc/row).
// R8: (a) pivot inversion DE-FUSED into its own gj_pivot kernel (gj_apply is
// now pure tile GEMM; the inversion cost becomes a visible dispatch);
// (b) broadcasts batched 8-wide (8 readlanes into 8 temps, then 8 fma) to
// amortize the SGPR hazard. Per-row expression unchanged -> numerics identical.
// R9: identical resubmit — R8 bench died to a container/broker failure (no
// kernel data); audit found no hang/crash vector in the kernel itself.

#define NF 8
#define TBINS 512
#define NNEU 512
#define NTRI 128
#define PAD 68

// ---- ws layout (float offsets) ----
#define OFF_A0     0                 // float[8*512*512] ping (reused as term1 partials)
#define OFF_A1     2097152           // float[8*512*512] pong
#define OFF_CRVT   4194304           // float[512*8]
#define OFF_CRVVT  4198400           // float[512*8]
#define OFF_CCT    4202496           // float[64]
#define OFF_CD     4202560           // float[64]
#define OFF_CDV    4202624           // float[64]
#define OFF_RINV   4202688           // float[512]
#define OFF_LAM    4203200           // float[8]
#define OFF_VF     4203216           // float[64]
#define OFF_BT     4203280           // float[4096*128]
#define OFF_XT     4727568           // float[4096*128]
#define OFF_PP0    5251856           // float[8*4096] pivot-inverse buf A
#define OFF_PP1    5284624           // float[8*4096] pivot-inverse buf B

__device__ __forceinline__ void load8(float* v, const float* ptr){
  float4 a = ((const float4*)ptr)[0];
  float4 b = ((const float4*)ptr)[1];
  v[0]=a.x; v[1]=a.y; v[2]=a.z; v[3]=a.w;
  v[4]=b.x; v[5]=b.y; v[6]=b.z; v[7]=b.w;
}
__device__ __forceinline__ void store8(float* ptr, const float* v){
  ((float4*)ptr)[0] = make_float4(v[0],v[1],v[2],v[3]);
  ((float4*)ptr)[1] = make_float4(v[4],v[5],v[6],v[7]);
}

__device__ __forceinline__ float rlane(float v, int l){
  return __int_as_float(__builtin_amdgcn_readlane(__float_as_int(v), l));
}

// ---------------- named-scalar machinery ----------------
#define REP64A(M) M(0) M(1) M(2) M(3) M(4) M(5) M(6) M(7) M(8) M(9) M(10) M(11) M(12) M(13) M(14) M(15) \
  M(16) M(17) M(18) M(19) M(20) M(21) M(22) M(23) M(24) M(25) M(26) M(27) M(28) M(29) M(30) M(31) \
  M(32) M(33) M(34) M(35) M(36) M(37) M(38) M(39) M(40) M(41) M(42) M(43) M(44) M(45) M(46) M(47) \
  M(48) M(49) M(50) M(51) M(52) M(53) M(54) M(55) M(56) M(57) M(58) M(59) M(60) M(61) M(62) M(63)

#define DECLC(i) float c##i;

// batch-8 fused update+rotate: 8 independent readlane broadcasts into temps,
// then 8 select+fma writes to reg (src-1). Reads captured before writes; within
// and across batches reg (s-1) was already consumed when written.
// Per-row math identical to R4/R6: c_{p-1} = fma(-pc, t0, iskk?0:c_p).
#define GJ_B8(s1,d1,s2,d2,s3,d3,s4,d4,s5,d5,s6,d6,s7,d7,s8,d8) { \
  float q1=rlane(c##s1,kk), q2=rlane(c##s2,kk), q3=rlane(c##s3,kk), q4=rlane(c##s4,kk), \
        q5=rlane(c##s5,kk), q6=rlane(c##s6,kk), q7=rlane(c##s7,kk), q8=rlane(c##s8,kk); \
  float e1=iskk?0.0f:c##s1, e2=iskk?0.0f:c##s2, e3=iskk?0.0f:c##s3, e4=iskk?0.0f:c##s4, \
        e5=iskk?0.0f:c##s5, e6=iskk?0.0f:c##s6, e7=iskk?0.0f:c##s7, e8=iskk?0.0f:c##s8; \
  c##d1=fmaf(-q1,t0,e1); c##d2=fmaf(-q2,t0,e2); c##d3=fmaf(-q3,t0,e3); c##d4=fmaf(-q4,t0,e4); \
  c##d5=fmaf(-q5,t0,e5); c##d6=fmaf(-q6,t0,e6); c##d7=fmaf(-q7,t0,e7); c##d8=fmaf(-q8,t0,e8); }

#define GJ_B7(s1,d1,s2,d2,s3,d3,s4,d4,s5,d5,s6,d6,s7,d7) { \
  float q1=rlane(c##s1,kk), q2=rlane(c##s2,kk), q3=rlane(c##s3,kk), q4=rlane(c##s4,kk), \
        q5=rlane(c##s5,kk), q6=rlane(c##s6,kk), q7=rlane(c##s7,kk); \
  float e1=iskk?0.0f:c##s1, e2=iskk?0.0f:c##s2, e3=iskk?0.0f:c##s3, e4=iskk?0.0f:c##s4, \
        e5=iskk?0.0f:c##s5, e6=iskk?0.0f:c##s6, e7=iskk?0.0f:c##s7; \
  c##d1=fmaf(-q1,t0,e1); c##d2=fmaf(-q2,t0,e2); c##d3=fmaf(-q3,t0,e3); c##d4=fmaf(-q4,t0,e4); \
  c##d5=fmaf(-q5,t0,e5); c##d6=fmaf(-q6,t0,e6); c##d7=fmaf(-q7,t0,e7); }

// 64-step rotation GJ over named scalars c0..c63 (lane = column index);
// pivot row always in c0 (reg p holds row (p+kk)%64).
#define GJ_LOOP \
  for (int kk = 0; kk < 64; ++kk){ \
    float pivot = rlane(c0, kk); \
    float pinv  = 1.0f / pivot; \
    bool  iskk  = (lane == kk); \
    float newr  = c0 * pinv; \
    float t0    = iskk ? pinv : newr; \
    GJ_B8(1,0,2,1,3,2,4,3,5,4,6,5,7,6,8,7) \
    GJ_B8(9,8,10,9,11,10,12,11,13,12,14,13,15,14,16,15) \
    GJ_B8(17,16,18,17,19,18,20,19,21,20,22,21,23,22,24,23) \
    GJ_B8(25,24,26,25,27,26,28,27,29,28,30,29,31,30,32,31) \
    GJ_B8(33,32,34,33,35,34,36,35,37,36,38,37,39,38,40,39) \
    GJ_B8(41,40,42,41,43,42,44,43,45,44,46,45,47,46,48,47) \
    GJ_B8(49,48,50,49,51,50,52,51,53,52,54,53,55,54,56,55) \
    GJ_B7(57,56,58,57,59,58,60,59,61,60,62,61,63,62) \
    c63 = t0; \
  }

// ---------------- prep ----------------
__global__ void prep_kernel(const float* __restrict__ Cm, const float* __restrict__ dm,
                            const float* __restrict__ r_diag,
                            float* __restrict__ crvT, float* __restrict__ ccT,
                            float* __restrict__ cd, float* __restrict__ rinv){
  __shared__ float s_crv[NNEU*NF];
  __shared__ float s_cm[NNEU*NF];
  __shared__ float s_dm[NNEU];
  int tid = threadIdx.x;            // 512; thread == neuron n
  float ri = 1.0f / r_diag[tid];
  rinv[tid] = ri;
  s_dm[tid] = dm[tid];
  #pragma unroll
  for (int f = 0; f < NF; ++f){
    float cv = Cm[tid*NF + f];
    s_cm[tid*NF + f] = cv;
    float v = cv * ri;
    s_crv[tid*NF + f] = v;
    crvT[tid*NF + f] = v;
  }
  __syncthreads();
  if (tid < 64){
    int f = tid >> 3, g = tid & 7;
    float acc = 0.f;
    for (int n = 0; n < NNEU; ++n) acc += s_crv[n*NF+f] * s_cm[n*NF+g];
    ccT[tid] = acc;
  } else if (tid < 72){
    int f = tid - 64;
    float acc = 0.f;
    for (int n = 0; n < NNEU; ++n) acc += s_crv[n*NF+f] * s_dm[n];
    cd[f] = acc;
  }
}

// ---------------- 8x8 eig: cyclic Jacobi, wave-parallel, fp32 ----------------
__global__ void eig8_kernel(const float* __restrict__ ccT,
                            float* __restrict__ Vf, float* __restrict__ lam){
  int lane = threadIdx.x & 63;      // one wave, 64 lanes
  int a = lane >> 3, b = lane & 7;
  float Av = ccT[lane];
  float Vv = (a == b) ? 1.0f : 0.0f;
  for (int sw = 0; sw < 8; ++sw){
    for (int p = 0; p < 7; ++p){
      for (int q = p + 1; q < 8; ++q){
        float apq = __shfl(Av, p*8 + q, 64);
        if (fabsf(apq) < 1e-20f) continue;          // uniform: apq is wave-broadcast
        float app = __shfl(Av, p*8 + p, 64);
        float aqq = __shfl(Av, q*8 + q, 64);
        float beta = (aqq - app) / (2.0f * apq);
        float tt = ((beta >= 0.0f) ? 1.0f : -1.0f) / (fabsf(beta) + sqrtf(1.0f + beta*beta));
        float c = 1.0f / sqrtf(1.0f + tt*tt);
        float s = tt * c;
        int bp = (b == p) ? q : (b == q) ? p : b;   // partner column
        float Ac = __shfl(Av, a*8 + bp, 64);        // snapshot before writes
        float Vc = __shfl(Vv, a*8 + bp, 64);
        if (b == p)      { Av = c*Av - s*Ac;  Vv = c*Vv - s*Vc; }
        else if (b == q) { Av = s*Ac + c*Av;  Vv = s*Vc + c*Vv; }
        int ap = (a == p) ? q : (a == q) ? p : a;   // partner row
        float Ar = __shfl(Av, ap*8 + b, 64);
        if (a == p)      Av = c*Av - s*Ar;
        else if (a == q) Av = s*Ar + c*Av;
      }
    }
  }
  if (a == b) lam[a] = Av;
  Vf[lane] = Vv;
}

// ---------------- rotate crv, cd by V^T ----------------
__global__ void rotv_kernel(const float* __restrict__ crvT, const float* __restrict__ cd,
                            const float* __restrict__ Vf,
                            float* __restrict__ crvVT, float* __restrict__ cdV){
  __shared__ float Vl[64];
  int tid = threadIdx.x;   // 512
  if (tid < 64) Vl[tid] = Vf[tid];
  __syncthreads();
  float cv[8], ov[8];
  load8(cv, crvT + tid*8);
  #pragma unroll
  for (int i = 0; i < 8; ++i){
    float s = 0.f;
    #pragma unroll
    for (int f = 0; f < 8; ++f) s += Vl[f*8+i] * cv[f];
    ov[i] = s;
  }
  store8(crvVT + tid*8, ov);
  if (tid < 8){
    float s = 0.f;
    #pragma unroll
    for (int f = 0; f < 8; ++f) s += Vl[f*8+tid] * cd[f];
    cdV[tid] = s;
  }
}

// ---------------- build K_f (fp32) ----------------
__global__ void buildK_kernel(const float* __restrict__ gamma, float* __restrict__ A0){
  int f = blockIdx.y;
  int idx = blockIdx.x*256 + threadIdx.x;   // t*512+u
  int t = idx >> 9, u = idx & 511;
  float g = gamma[f];
  float d = (float)(t - u);
  float v = 0.999f * expf(-0.5f * g * d * d);
  if (t == u) v += 1.0e-3f;
  A0[(size_t)f*TBINS*TBINS + idx] = v;
}

// ---------------- G_i = (sum_f Kinv_f) + lam_i I ----------------
__global__ void buildG_kernel(const float* __restrict__ A0, const float* __restrict__ lam,
                              float* __restrict__ A1){
  int idx = blockIdx.x*256 + threadIdx.x;       // 0..262143
  float s = 0.f;
  #pragma unroll
  for (int f2 = 0; f2 < NF; ++f2) s += A0[(size_t)f2*TBINS*TBINS + idx];
  bool diag = ((idx >> 9) == (idx & 511));
  #pragma unroll
  for (int i = 0; i < NF; ++i)
    A1[(size_t)i*TBINS*TBINS + idx] = s + (diag ? lam[i] : 0.f);
}

// ---------------- pivot inversion: Pout[f] = inv(A[f][k1*64:..][k1*64:..]) ----------------
// One wave per factor; lane owns column `lane`, rows in rotating named scalars.
// Standalone dispatch (de-fused from gj_apply) so its cost is directly visible.
__global__ __launch_bounds__(64) void gj_pivot(const float* __restrict__ A,
                                               float* __restrict__ Pout, int k1){
  int f = blockIdx.x;
  int lane = threadIdx.x;           // 64
  const float* Af = A + (size_t)f*TBINS*TBINS + (size_t)(k1*64)*TBINS + k1*64;
  REP64A(DECLC)
  #define LOADG(i) c##i = Af[(size_t)(i)*TBINS + lane];
  REP64A(LOADG)
  #undef LOADG
  GJ_LOOP
  #define STOREC(i) Pout[(f<<12) + (i)*64 + lane] = c##i;
  REP64A(STOREC)
  #undef STOREC
}

// ---------------- GJ apply step: src -> dst (pure tile GEMMs) ----------------
#define ACC4(tm, fm) \
  tm[0] += fm.x*s0.x + fm.y*s1.x + fm.z*s2.x + fm.w*s3.x; \
  tm[1] += fm.x*s0.y + fm.y*s1.y + fm.z*s2.y + fm.w*s3.y; \
  tm[2] += fm.x*s0.z + fm.y*s1.z + fm.z*s2.z + fm.w*s3.z; \
  tm[3] += fm.x*s0.w + fm.y*s1.w + fm.z*s2.w + fm.w*s3.w;

__global__ __launch_bounds__(256) void gj_apply(const float* __restrict__ src,
                                                float* __restrict__ dst,
                                                const float* __restrict__ Pin,
                                                int k){
  __shared__ float P[64*PAD];
  __shared__ float Q[64*PAD];
  __shared__ float F[64*PAD];
  int f  = blockIdx.y;
  int ti = blockIdx.x >> 3, tj = blockIdx.x & 7;
  int tid = threadIdx.x;
  const float* A = src + (size_t)f*TBINS*TBINS;
  float* D = dst + (size_t)f*TBINS*TBINS;

  // load pivot inverse (precomputed)
  for (int v = tid; v < 1024; v += 256){
    int r = v >> 4, c4 = (v & 15) << 2;
    *(float4*)&P[r*PAD + c4] = *(const float4*)(Pin + f*4096 + r*64 + c4);
  }
  if (tj != k){
    for (int v = tid; v < 1024; v += 256){
      int r = v >> 4, c4 = (v & 15) << 2;
      *(float4*)&Q[r*PAD + c4] = *(const float4*)(A + (size_t)(k*64+r)*TBINS + tj*64 + c4);
    }
  }
  if (ti != k){
    for (int v = tid; v < 1024; v += 256){
      int r = v >> 4, c4 = (v & 15) << 2;
      *(float4*)&F[r*PAD + c4] = *(const float4*)(A + (size_t)(ti*64+r)*TBINS + k*64 + c4);
    }
  }
  __syncthreads();

  int jg = (tid & 15) << 2;   // output cols jg..jg+3
  int ib = (tid >> 4) << 2;   // output rows ib..ib+3

  if (tj == k){
    if (ti == k){
      // pass-through: D[k][k] = P
      for (int v = tid; v < 1024; v += 256){
        int r = v >> 4, c4 = (v & 15) << 2;
        *(float4*)(D + (size_t)(k*64+r)*TBINS + k*64 + c4) = *(float4*)&P[r*PAD + c4];
      }
      return;
    }
    // D = -F @ P
    float w[4][4] = {{0.f,0.f,0.f,0.f},{0.f,0.f,0.f,0.f},{0.f,0.f,0.f,0.f},{0.f,0.f,0.f,0.f}};
    for (int u4 = 0; u4 < 64; u4 += 4){
      float4 f0 = *(float4*)&F[(ib+0)*PAD + u4];
      float4 f1 = *(float4*)&F[(ib+1)*PAD + u4];
      float4 f2 = *(float4*)&F[(ib+2)*PAD + u4];
      float4 f3 = *(float4*)&F[(ib+3)*PAD + u4];
      float4 s0 = *(float4*)&P[(u4+0)*PAD + jg];
      float4 s1 = *(float4*)&P[(u4+1)*PAD + jg];
      float4 s2 = *(float4*)&P[(u4+2)*PAD + jg];
      float4 s3 = *(float4*)&P[(u4+3)*PAD + jg];
      ACC4(w[0], f0); ACC4(w[1], f1); ACC4(w[2], f2); ACC4(w[3], f3);
    }
    #pragma unroll
    for (int m = 0; m < 4; ++m)
      *(float4*)(D + (size_t)(ti*64+ib+m)*TBINS + k*64 + jg)
        = make_float4(-w[m][0], -w[m][1], -w[m][2], -w[m][3]);
    return;
  }

  // tj != k: T = P @ Q (P symmetric: P'[ib][u] = P[u][ib])
  float t[4][4] = {{0.f,0.f,0.f,0.f},{0.f,0.f,0.f,0.f},{0.f,0.f,0.f,0.f},{0.f,0.f,0.f,0.f}};
  for (int u = 0; u < 64; ++u){
    float4 pv = *(float4*)&P[u*PAD + ib];
    float4 qv = *(float4*)&Q[u*PAD + jg];
    t[0][0]+=pv.x*qv.x; t[0][1]+=pv.x*qv.y; t[0][2]+=pv.x*qv.z; t[0][3]+=pv.x*qv.w;
    t[1][0]+=pv.y*qv.x; t[1][1]+=pv.y*qv.y; t[1][2]+=pv.y*qv.z; t[1][3]+=pv.y*qv.w;
    t[2][0]+=pv.z*qv.x; t[2][1]+=pv.z*qv.y; t[2][2]+=pv.z*qv.z; t[2][3]+=pv.z*qv.w;
    t[3][0]+=pv.w*qv.x; t[3][1]+=pv.w*qv.y; t[3][2]+=pv.w*qv.z; t[3][3]+=pv.w*qv.w;
  }
  if (ti == k){
    // D = T directly from registers
    #pragma unroll
    for (int m = 0; m < 4; ++m)
      *(float4*)(D + (size_t)(k*64+ib+m)*TBINS + tj*64 + jg)
        = make_float4(t[m][0],t[m][1],t[m][2],t[m][3]);
    return;
  }
  __syncthreads();               // all reads of Q done
  #pragma unroll
  for (int m = 0; m < 4; ++m)
    *(float4*)&Q[(ib+m)*PAD + jg] = make_float4(t[m][0],t[m][1],t[m][2],t[m][3]);
  __syncthreads();               // T visible to all

  // Schur: D = A[ti][tj] - F @ T
  float w[4][4] = {{0.f,0.f,0.f,0.f},{0.f,0.f,0.f,0.f},{0.f,0.f,0.f,0.f},{0.f,0.f,0.f,0.f}};
  for (int u4 = 0; u4 < 64; u4 += 4){
    float4 f0 = *(float4*)&F[(ib+0)*PAD + u4];
    float4 f1 = *(float4*)&F[(ib+1)*PAD + u4];
    float4 f2 = *(float4*)&F[(ib+2)*PAD + u4];
    float4 f3 = *(float4*)&F[(ib+3)*PAD + u4];
    float4 s0 = *(float4*)&Q[(u4+0)*PAD + jg];
    float4 s1 = *(float4*)&Q[(u4+1)*PAD + jg];
    float4 s2 = *(float4*)&Q[(u4+2)*PAD + jg];
    float4 s3 = *(float4*)&Q[(u4+3)*PAD + jg];
    ACC4(w[0], f0); ACC4(w[1], f1); ACC4(w[2], f2); ACC4(w[3], f3);
  }
  #pragma unroll
  for (int m = 0; m < 4; ++m){
    float4 av = *(const float4*)(A + (size_t)(ti*64+ib+m)*TBINS + tj*64 + jg);
    *(float4*)(D + (size_t)(ti*64+ib+m)*TBINS + tj*64 + jg)
      = make_float4(av.x - w[m][0], av.y - w[m][1], av.z - w[m][2], av.w - w[m][3]);
  }
}

// ---------------- term1 (chunked): btp[z][(t*8+i)*128+c] = sum_{n in chunk z} crvV[i][n] spike[c][n][t]
__global__ void term1_kernel(const float* __restrict__ spike, const float* __restrict__ crvVT,
                             float* __restrict__ btp){
  __shared__ float crl[128*NF];    // this chunk's [n][i]
  __shared__ float ot[128][17];
  int t0 = blockIdx.x * 16;
  int c0 = blockIdx.y * 16;
  int n0 = blockIdx.z << 7;        // 128-neuron chunk
  int tid = threadIdx.x;           // 256
  int tl = tid & 15, cl = tid >> 4;
  ((float4*)crl)[tid] = ((const float4*)(crvVT + n0*NF))[tid];   // 1024 floats
  __syncthreads();
  float acc[8] = {0.f,0.f,0.f,0.f,0.f,0.f,0.f,0.f};
  const float* Sp = spike + (size_t)(c0+cl)*NNEU*TBINS + (size_t)n0*TBINS + t0 + tl;
  for (int n = 0; n < 128; n += 8){
    float s[8];
    #pragma unroll
    for (int j = 0; j < 8; ++j) s[j] = Sp[(size_t)(n+j)*TBINS];   // 8 loads in flight
    #pragma unroll
    for (int j = 0; j < 8; ++j){
      float4 ca = *(float4*)&crl[(n+j)*8];
      float4 cb = *(float4*)&crl[(n+j)*8+4];
      acc[0] += ca.x*s[j]; acc[1] += ca.y*s[j]; acc[2] += ca.z*s[j]; acc[3] += ca.w*s[j];
      acc[4] += cb.x*s[j]; acc[5] += cb.y*s[j]; acc[6] += cb.z*s[j]; acc[7] += cb.w*s[j];
    }
  }
  #pragma unroll
  for (int i = 0; i < 8; ++i) ot[tl*8+i][cl] = acc[i];
  __syncthreads();
  int row = tid >> 1, off = (tid & 1) * 8;    // row = tlocal*8+i
  int tt = t0 + (row >> 3), ii = row & 7;
  float* dst = btp + (size_t)blockIdx.z*524288 + (size_t)(tt*8+ii)*NTRI + c0 + off;
  #pragma unroll
  for (int k = 0; k < 8; ++k) dst[k] = ot[row][off+k];
}

// ---------------- term1 reduce: bt = sum_z btp[z] - cdV[i] ----------------
__global__ void term1_reduce(const float* __restrict__ btp, const float* __restrict__ cdV,
                             float* __restrict__ bt){
  int idx = blockIdx.x*256 + threadIdx.x;   // float4 index, 131072 total
  const float4* p = (const float4*)btp;
  float4 a = p[idx];
  float4 b = p[idx + 131072];
  float4 c = p[idx + 262144];
  float4 d = p[idx + 393216];
  float cv = cdV[(idx >> 5) & 7];           // i = ((t*8+i)*32 + c4)>>5 & 7
  ((float4*)bt)[idx] = make_float4(a.x+b.x+c.x+d.x - cv,
                                   a.y+b.y+c.y+d.y - cv,
                                   a.z+b.z+c.z+d.z - cv,
                                   a.w+b.w+c.w+d.w - cv);
}

// ---------------- batched GEMM: xt_i = H_i (512x512) @ bt_i (512x128) ----------------
__global__ void gemm_kernel(const float* __restrict__ H, const float* __restrict__ bt,
                            float* __restrict__ xt){
  __shared__ float Ht[32][68];
  __shared__ float Bt[64][128];
  int i  = blockIdx.y;
  int t0 = blockIdx.x * 32;
  int tid = threadIdx.x;           // 256
  int gt = tid >> 5;               // 0..7
  int gc = tid & 31;               // 0..31
  float acc[4][4] = {{0.f,0.f,0.f,0.f},{0.f,0.f,0.f,0.f},{0.f,0.f,0.f,0.f},{0.f,0.f,0.f,0.f}};
  const float* Hi = H + (size_t)i*TBINS*TBINS;
  for (int uc = 0; uc < 8; ++uc){
    int u0 = uc*64;
    __syncthreads();
    for (int v = tid; v < 512; v += 256){
      int r = v >> 4, c4 = (v & 15) << 2;
      *(float4*)&Ht[r][c4] = *(const float4*)(Hi + (size_t)(t0+r)*TBINS + u0 + c4);
    }
    for (int v = tid; v < 2048; v += 256){
      int r = v >> 5, c4 = (v & 31) << 2;
      *(float4*)&Bt[r][c4] = *(const float4*)(bt + (size_t)((u0+r)*8 + i)*NTRI + c4);
    }
    __syncthreads();
    for (int u = 0; u < 64; ++u){
      float h0 = Ht[gt*4+0][u], h1 = Ht[gt*4+1][u], h2 = Ht[gt*4+2][u], h3 = Ht[gt*4+3][u];
      float b0 = Bt[u][gc], b1 = Bt[u][gc+32], b2 = Bt[u][gc+64], b3 = Bt[u][gc+96];
      acc[0][0] += h0*b0; acc[0][1] += h0*b1; acc[0][2] += h0*b2; acc[0][3] += h0*b3;
      acc[1][0] += h1*b0; acc[1][1] += h1*b1; acc[1][2] += h1*b2; acc[1][3] += h1*b3;
      acc[2][0] += h2*b0; acc[2][1] += h2*b1; acc[2][2] += h2*b2; acc[2][3] += h2*b3;
      acc[3][0] += h3*b0; acc[3][1] += h3*b1; acc[3][2] += h3*b2; acc[3][3] += h3*b3;
    }
  }
  #pragma unroll
  for (int m = 0; m < 4; ++m)
    #pragma unroll
    for (int j = 0; j < 4; ++j)
      xt[(size_t)((t0 + gt*4 + m)*8 + i)*NTRI + gc + 32*j] = acc[m][j];
}

// ---------------- output: out[c][f][t] = sum_i V[f][i] xt[(t*8+i)*128+c] ----------------
__global__ void output_kernel(const float* __restrict__ xt, const float* __restrict__ Vf,
                              float* __restrict__ out){
  __shared__ float T[128][68];
  __shared__ float Vl[64];
  int t0 = blockIdx.x * 64, c0 = blockIdx.y * 16;
  int tid = threadIdx.x;   // 256
  if (tid < 64) Vl[tid] = Vf[tid];
  __syncthreads();
  for (int idx = tid; idx < 1024; idx += 256){
    int tl = idx >> 4, cl = idx & 15;
    float xv[8];
    #pragma unroll
    for (int i = 0; i < 8; ++i)
      xv[i] = xt[(size_t)((t0+tl)*8+i)*NTRI + c0 + cl];
    #pragma unroll
    for (int f = 0; f < 8; ++f){
      float s = 0.f;
      #pragma unroll
      for (int i = 0; i < 8; ++i) s += Vl[f*8+i] * xv[i];
      T[cl*8+f][tl] = s;
    }
  }
  __syncthreads();
  int row = tid >> 1, half = tid & 1;   // row = cl*8+f
  int cc = c0 + (row >> 3), ff = row & 7;
  float* dst = out + (size_t)cc*NF*TBINS + ff*TBINS + t0 + half*32;
  #pragma unroll
  for (int k = 0; k < 8; ++k)
    ((float4*)dst)[k] = *(float4*)&T[row][half*32 + k*4];
}

extern "C" void kernel_launch(void* const* d_in, const int* in_sizes, int n_in,
                              void* d_out, int out_size, void* d_ws, size_t ws_size,
                              hipStream_t stream) {
  const float* spike  = (const float*)d_in[0];
  const float* Cm     = (const float*)d_in[1];
  const float* dm     = (const float*)d_in[2];
  const float* r_diag = (const float*)d_in[3];
  const float* gamma  = (const float*)d_in[4];
  float* out = (float*)d_out;
  float* ws = (float*)d_ws;

  float*  A0    = ws + OFF_A0;
  float*  A1    = ws + OFF_A1;
  float*  crvT  = ws + OFF_CRVT;
  float*  crvVT = ws + OFF_CRVVT;
  float*  ccT   = ws + OFF_CCT;
  float*  cd    = ws + OFF_CD;
  float*  cdV   = ws + OFF_CDV;
  float*  rinv  = ws + OFF_RINV;
  float*  lam   = ws + OFF_LAM;
  float*  Vf    = ws + OFF_VF;
  float*  bt    = ws + OFF_BT;
  float*  xt    = ws + OFF_XT;
  float*  Pb[2] = { ws + OFF_PP0, ws + OFF_PP1 };

  prep_kernel<<<1, 512, 0, stream>>>(Cm, dm, r_diag, crvT, ccT, cd, rinv);
  eig8_kernel<<<1, 64, 0, stream>>>(ccT, Vf, lam);
  rotv_kernel<<<1, 512, 0, stream>>>(crvT, cd, Vf, crvVT, cdV);
  buildK_kernel<<<dim3(1024, 8), 256, 0, stream>>>(gamma, A0);

  // chain 1: invert K_f (ping-pong A0 <-> A1, 8 steps -> result in A0)
  gj_pivot<<<8, 64, 0, stream>>>(A0, Pb[0], 0);
  {
    float* s = A0; float* d = A1;
    for (int k = 0; k < 8; ++k){
      gj_apply<<<dim3(64, 8), 256, 0, stream>>>(s, d, Pb[k&1], k);
      if (k < 7) gj_pivot<<<8, 64, 0, stream>>>(d, Pb[(k+1)&1], k+1);
      float* tmp = s; s = d; d = tmp;
    }
  }
  buildG_kernel<<<1024, 256, 0, stream>>>(A0, lam, A1);
  // chain 2: invert G_i (start A1, 8 steps -> H in A1; A0 dead afterwards)
  gj_pivot<<<8, 64, 0, stream>>>(A1, Pb[0], 0);
  {
    float* s = A1; float* d = A0;
    for (int k = 0; k < 8; ++k){
      gj_apply<<<dim3(64, 8), 256, 0, stream>>>(s, d, Pb[k&1], k);
      if (k < 7) gj_pivot<<<8, 64, 0, stream>>>(d, Pb[(k+1)&1], k+1);
      float* tmp = s; s = d; d = tmp;
    }
  }
  term1_kernel<<<dim3(32, 8, 4), 256, 0, stream>>>(spike, crvVT, A0);
  term1_reduce<<<512, 256, 0, stream>>>(A0, cdV, bt);
  gemm_kernel<<<dim3(16, 8), 256, 0, stream>>>(A1, bt, xt);
  output_kernel<<<dim3(8, 8), 256, 0, stream>>>(xt, Vf, out);
}